// Round 1
// baseline (668.405 us; speedup 1.0000x reference)
//
#include <hip/hip_runtime.h>
#include <hip/hip_bf16.h>

#define LSTM_H 16
#define SEQ_T 7

// --- fast activations on v_exp_f32 (exp2) + v_rcp_f32, overflow-safe ---
__device__ __forceinline__ float sigmoidf_fast(float x) {
    // 1/(1+exp(-x)) = rcp(1 + exp2(-x*log2e))
    float e = __builtin_amdgcn_exp2f(-1.442695040888963f * x);
    return __builtin_amdgcn_rcpf(1.0f + e);
}
__device__ __forceinline__ float tanhf_fast(float x) {
    // tanh(x) = 1 - 2/(exp2(2x*log2e)+1); e->inf => 1, e->0 => -1 (no NaN)
    float e = __builtin_amdgcn_exp2f(2.885390081777927f * x);
    return 1.0f - 2.0f * __builtin_amdgcn_rcpf(e + 1.0f);
}

__global__ __launch_bounds__(256) void infect_lstm_kernel(
    const float* __restrict__ mobility,  // [B,7]
    const float* __restrict__ controls,  // [B,5]
    const float* __restrict__ W_cc,      // [3,5]
    const float* __restrict__ b_cc,      // [3]
    const float* __restrict__ W_ih,      // [64]
    const float* __restrict__ W_hh,      // [64,16]
    const float* __restrict__ b_ih,      // [64]
    const float* __restrict__ b_hh,      // [64]
    const float* __restrict__ W1,        // [16,19]
    const float* __restrict__ b1,        // [16]
    const float* __restrict__ W2,        // [16,16]
    const float* __restrict__ b2,        // [16]
    const float* __restrict__ W3,        // [16]
    const float* __restrict__ b3,        // [1]
    float* __restrict__ out,             // [B]
    int Btot)
{
    const int row = blockIdx.x * blockDim.x + threadIdx.x;
    if (row >= Btot) return;

    // ---- per-row inputs (L1/L2 absorb the modest non-coalescing; op is compute-bound) ----
    float mob[SEQ_T];
    #pragma unroll
    for (int t = 0; t < SEQ_T; ++t) mob[t] = mobility[row * SEQ_T + t];
    float ctl[5];
    #pragma unroll
    for (int k = 0; k < 5; ++k) ctl[k] = controls[row * 5 + k];

    // ---- control head: Linear(5->3) ----
    float control[3];
    #pragma unroll
    for (int j = 0; j < 3; ++j) {
        float acc = b_cc[j];
        #pragma unroll
        for (int k = 0; k < 5; ++k) acc = fmaf(ctl[k], W_cc[j * 5 + k], acc);
        control[j] = acc;
    }

    // ---- LSTM(input=1, hidden=16), 7 steps, gate order i,f,g,o ----
    float h[LSTM_H], c[LSTM_H];
    #pragma unroll
    for (int n = 0; n < LSTM_H; ++n) { h[n] = 0.0f; c[n] = 0.0f; }

    #pragma unroll 1   // keep body ~1.1K VALU instrs -> fits I$; weights re-read via K$-cached s_load
    for (int t = 0; t < SEQ_T; ++t) {
        const float xt = mob[t];
        float hn[LSTM_H];
        #pragma unroll
        for (int n = 0; n < LSTM_H; ++n) {
            float gi = b_ih[n]      + b_hh[n]      + xt * W_ih[n];
            float gf = b_ih[16 + n] + b_hh[16 + n] + xt * W_ih[16 + n];
            float gg = b_ih[32 + n] + b_hh[32 + n] + xt * W_ih[32 + n];
            float go = b_ih[48 + n] + b_hh[48 + n] + xt * W_ih[48 + n];
            #pragma unroll
            for (int k = 0; k < LSTM_H; ++k) {
                const float hk = h[k];
                gi = fmaf(hk, W_hh[(n)      * 16 + k], gi);
                gf = fmaf(hk, W_hh[(16 + n) * 16 + k], gf);
                gg = fmaf(hk, W_hh[(32 + n) * 16 + k], gg);
                go = fmaf(hk, W_hh[(48 + n) * 16 + k], go);
            }
            const float ig = sigmoidf_fast(gi);
            const float fg = sigmoidf_fast(gf);
            const float gg2 = tanhf_fast(gg);
            const float og = sigmoidf_fast(go);
            const float cn = fg * c[n] + ig * gg2;
            c[n] = cn;
            hn[n] = og * tanhf_fast(cn);
        }
        #pragma unroll
        for (int n = 0; n < LSTM_H; ++n) h[n] = hn[n];
    }

    // ---- fc: Linear(19->16) Tanh -> Linear(16->16) Tanh -> Linear(16->1) ReLU ----
    float x19[19];
    #pragma unroll
    for (int n = 0; n < LSTM_H; ++n) x19[n] = h[n];
    #pragma unroll
    for (int j = 0; j < 3; ++j) x19[16 + j] = control[j];

    float t1[16];
    #pragma unroll
    for (int j = 0; j < 16; ++j) {
        float acc = b1[j];
        #pragma unroll
        for (int k = 0; k < 19; ++k) acc = fmaf(x19[k], W1[j * 19 + k], acc);
        t1[j] = tanhf_fast(acc);
    }
    float t2[16];
    #pragma unroll
    for (int j = 0; j < 16; ++j) {
        float acc = b2[j];
        #pragma unroll
        for (int k = 0; k < 16; ++k) acc = fmaf(t1[k], W2[j * 16 + k], acc);
        t2[j] = tanhf_fast(acc);
    }
    float acc = b3[0];
    #pragma unroll
    for (int k = 0; k < 16; ++k) acc = fmaf(t2[k], W3[k], acc);
    out[row] = fmaxf(acc, 0.0f);
}

extern "C" void kernel_launch(void* const* d_in, const int* in_sizes, int n_in,
                              void* d_out, int out_size, void* d_ws, size_t ws_size,
                              hipStream_t stream) {
    const float* mobility = (const float*)d_in[0];
    const float* controls = (const float*)d_in[1];
    // d_in[2] = last : unused by the reference
    const float* W_cc = (const float*)d_in[3];
    const float* b_cc = (const float*)d_in[4];
    const float* W_ih = (const float*)d_in[5];
    const float* W_hh = (const float*)d_in[6];
    const float* b_ih = (const float*)d_in[7];
    const float* b_hh = (const float*)d_in[8];
    const float* W1   = (const float*)d_in[9];
    const float* b1   = (const float*)d_in[10];
    const float* W2   = (const float*)d_in[11];
    const float* b2   = (const float*)d_in[12];
    const float* W3   = (const float*)d_in[13];
    const float* b3   = (const float*)d_in[14];
    float* out = (float*)d_out;

    const int Btot = in_sizes[0] / SEQ_T;  // 1048576
    const int block = 256;
    const int grid = (Btot + block - 1) / block;

    infect_lstm_kernel<<<grid, block, 0, stream>>>(
        mobility, controls, W_cc, b_cc, W_ih, W_hh, b_ih, b_hh,
        W1, b1, W2, b2, W3, b3, out, Btot);
}

// Round 2
// 476.758 us; speedup vs baseline: 1.4020x; 1.4020x over previous
//
#include <hip/hip_runtime.h>
#include <hip/hip_bf16.h>

typedef float v2f __attribute__((ext_vector_type(2)));

#define LOG2E 1.442695040888963f

// sigmoid(x) = rcp(1 + exp2(-x*log2e)); overflow-safe both directions
__device__ __forceinline__ float sig_fast(float x) {
    float e = __builtin_amdgcn_exp2f(-LOG2E * x);
    return __builtin_amdgcn_rcpf(1.0f + e);
}
// tanh(x) = 1 - 2*rcp(exp2(2x*log2e) + 1); e->inf => 1, e->0 => -1
__device__ __forceinline__ float tanh_fast(float x) {
    float e = __builtin_amdgcn_exp2f((2.0f * LOG2E) * x);
    return 1.0f - 2.0f * __builtin_amdgcn_rcpf(e + 1.0f);
}

__global__ __launch_bounds__(256) void infect_lstm_kernel(
    const float* __restrict__ mobility,  // [B,7]
    const float* __restrict__ controls,  // [B,5]
    const float* __restrict__ W_cc,      // [3,5]
    const float* __restrict__ b_cc,      // [3]
    const float* __restrict__ W_ih,      // [64]
    const float* __restrict__ W_hh,      // [64,16]
    const float* __restrict__ b_ih,      // [64]
    const float* __restrict__ b_hh,      // [64]
    const float* __restrict__ W1,        // [16,19]
    const float* __restrict__ b1,        // [16]
    const float* __restrict__ W2,        // [16,16]
    const float* __restrict__ b2,        // [16]
    const float* __restrict__ W3,        // [16]
    const float* __restrict__ b3,        // [1]
    float* __restrict__ out,             // [B]
    int Btot)
{
    // UNIFORM control flow: no early return (it would put every uniform weight
    // load under a divergent branch and block s_load promotion -> 4x slowdown).
    int row = blockIdx.x * blockDim.x + threadIdx.x;
    row = min(row, Btot - 1);

    // ---- per-row inputs (divergent, vector loads) ----
    float mob[7];
    #pragma unroll
    for (int t = 0; t < 7; ++t) mob[t] = mobility[row * 7 + t];
    float ctl[5];
    #pragma unroll
    for (int k = 0; k < 5; ++k) ctl[k] = controls[row * 5 + k];

    // ---- control head: Linear(5->3) ----
    float control[3];
    #pragma unroll
    for (int j = 0; j < 3; ++j) {
        float a = b_cc[j];
        #pragma unroll
        for (int k = 0; k < 5; ++k) a = fmaf(ctl[k], W_cc[j * 5 + k], a);
        control[j] = a;
    }

    // ---- hoisted gate bias (no scalar-float ALU on CDNA; do it once) ----
    float bias[64];
    #pragma unroll
    for (int j = 0; j < 64; ++j) bias[j] = b_ih[j] + b_hh[j];

    // ---- LSTM(1->16), 7 steps, gates i,f,g,o; k-dimension packed as float2 ----
    v2f h2[8];
    float c[16];
    #pragma unroll
    for (int p = 0; p < 8; ++p) h2[p] = (v2f)(0.0f);
    #pragma unroll
    for (int n = 0; n < 16; ++n) c[n] = 0.0f;

    #pragma unroll 1   // rolled: ~1K-instr body fits I$; weights re-read via K$ s_load
    for (int t = 0; t < 7; ++t) {
        const float xt = mob[t];
        v2f hn2[8];
        #pragma unroll
        for (int n = 0; n < 16; ++n) {
            float g4[4];
            #pragma unroll
            for (int g = 0; g < 4; ++g) {
                const v2f* wrow = (const v2f*)(W_hh + (g * 16 + n) * 16);
                v2f acc = h2[0] * wrow[0];
                #pragma unroll
                for (int p = 1; p < 8; ++p)
                    acc = __builtin_elementwise_fma(h2[p], wrow[p], acc);
                const float s = fmaf(xt, W_ih[g * 16 + n], bias[g * 16 + n]);
                g4[g] = s + acc.x + acc.y;
            }
            const float ig = sig_fast(g4[0]);
            const float fg = sig_fast(g4[1]);
            const float gg = tanh_fast(g4[2]);
            const float og = sig_fast(g4[3]);
            const float cn = fmaf(fg, c[n], ig * gg);
            c[n] = cn;
            hn2[n >> 1][n & 1] = og * tanh_fast(cn);
        }
        #pragma unroll
        for (int p = 0; p < 8; ++p) h2[p] = hn2[p];
    }

    // ---- fc1: Linear(19->16) + tanh (19 is odd -> scalar fma, stays s_load) ----
    float x19[19];
    #pragma unroll
    for (int n = 0; n < 16; ++n) x19[n] = h2[n >> 1][n & 1];
    #pragma unroll
    for (int j = 0; j < 3; ++j) x19[16 + j] = control[j];

    v2f t12[8];
    #pragma unroll
    for (int j = 0; j < 16; ++j) {
        float a = b1[j];
        #pragma unroll
        for (int k = 0; k < 19; ++k) a = fmaf(x19[k], W1[j * 19 + k], a);
        t12[j >> 1][j & 1] = tanh_fast(a);
    }

    // ---- fc2: Linear(16->16) + tanh (packed) ----
    v2f t22[8];
    #pragma unroll
    for (int j = 0; j < 16; ++j) {
        const v2f* w2row = (const v2f*)(W2 + j * 16);
        v2f a = t12[0] * w2row[0];
        #pragma unroll
        for (int p = 1; p < 8; ++p)
            a = __builtin_elementwise_fma(t12[p], w2row[p], a);
        t22[j >> 1][j & 1] = tanh_fast(a.x + a.y + b2[j]);
    }

    // ---- fc3: Linear(16->1) + ReLU (packed dot) ----
    const v2f* w3p = (const v2f*)W3;
    v2f a3 = t22[0] * w3p[0];
    #pragma unroll
    for (int p = 1; p < 8; ++p)
        a3 = __builtin_elementwise_fma(t22[p], w3p[p], a3);
    const float r = a3.x + a3.y + b3[0];
    out[row] = fmaxf(r, 0.0f);
}

extern "C" void kernel_launch(void* const* d_in, const int* in_sizes, int n_in,
                              void* d_out, int out_size, void* d_ws, size_t ws_size,
                              hipStream_t stream) {
    const float* mobility = (const float*)d_in[0];
    const float* controls = (const float*)d_in[1];
    // d_in[2] = last : unused by the reference
    const float* W_cc = (const float*)d_in[3];
    const float* b_cc = (const float*)d_in[4];
    const float* W_ih = (const float*)d_in[5];
    const float* W_hh = (const float*)d_in[6];
    const float* b_ih = (const float*)d_in[7];
    const float* b_hh = (const float*)d_in[8];
    const float* W1   = (const float*)d_in[9];
    const float* b1   = (const float*)d_in[10];
    const float* W2   = (const float*)d_in[11];
    const float* b2   = (const float*)d_in[12];
    const float* W3   = (const float*)d_in[13];
    const float* b3   = (const float*)d_in[14];
    float* out = (float*)d_out;

    const int Btot = in_sizes[0] / 7;  // 1048576
    const int block = 256;
    const int grid = (Btot + block - 1) / block;

    infect_lstm_kernel<<<grid, block, 0, stream>>>(
        mobility, controls, W_cc, b_cc, W_ih, W_hh, b_ih, b_hh,
        W1, b1, W2, b2, W3, b3, out, Btot);
}

// Round 4
// 168.359 us; speedup vs baseline: 3.9701x; 2.8318x over previous
//
#include <hip/hip_runtime.h>
#include <hip/hip_bf16.h>

typedef _Float16 f16x8 __attribute__((ext_vector_type(8)));
typedef float    f32x16 __attribute__((ext_vector_type(16)));
typedef float    v2f   __attribute__((ext_vector_type(2)));
typedef unsigned u32x4 __attribute__((ext_vector_type(4)));

#define LOG2E 1.442695040888963f

__device__ __forceinline__ float sig_fast(float x) {
    float e = __builtin_amdgcn_exp2f(-LOG2E * x);
    return __builtin_amdgcn_rcpf(1.0f + e);
}
__device__ __forceinline__ float tanh_fast(float x) {
    float e = __builtin_amdgcn_exp2f((2.0f * LOG2E) * x);
    return 1.0f - 2.0f * __builtin_amdgcn_rcpf(e + 1.0f);
}
__device__ __forceinline__ unsigned pk16(float a, float b) {
    // v_cvt_pkrtz_f16_f32: low16 = a, high16 = b
    return __builtin_bit_cast(unsigned, __builtin_amdgcn_cvt_pkrtz(a, b));
}

// Per wave: 64 batch rows. Per step t:
//   G^T[64 gu][64 rows] = W_hh[64x16] @ h^T[16x64]  (4x mfma_f32_32x32x16_f16)
// A = W_hh fragments (wave-constant, loaded once). B = h^T (repacked per step).
// D layout: col(=batch row)=lane&31, row(=gu)=(reg&3)+8*(reg>>2)+4*(lane>>5)
// -> lane holds i,f,g,o of units U = {0-3,8-11}+4*(lane>>5) for rows r_lo,r_hi.
__global__ __launch_bounds__(256) void lstm_mfma_kernel(
    const float* __restrict__ mobility,  // [B,7]
    const float* __restrict__ controls,  // [B,5]
    const float* __restrict__ W_cc, const float* __restrict__ b_cc,
    const float* __restrict__ W_ih, const float* __restrict__ W_hh,
    const float* __restrict__ b_ih, const float* __restrict__ b_hh,
    const float* __restrict__ W1,  const float* __restrict__ b1,
    const float* __restrict__ W2,  const float* __restrict__ b2,
    const float* __restrict__ W3,  const float* __restrict__ b3,
    float* __restrict__ out, int Btot)
{
    __shared__ float hbuf[256][16];   // 16 KB: final h, wave->thread redistribution

    const int tid  = threadIdx.x;
    const int lane = tid & 63;
    const int wib  = tid >> 6;        // wave in block
    const int col  = lane & 31;
    const int hi   = lane >> 5;

    const int blockRow0 = blockIdx.x * 256;
    const int r_lo = blockRow0 + wib * 64 + col;
    const int r_hi = r_lo + 32;

    // ---- A fragments: W_hh -> f16, once. A[m=gu][k]: m=lane&31, k=hi*8+e ----
    f16x8 afrag[2];
    #pragma unroll
    for (int gb = 0; gb < 2; ++gb) {
        const float* wr = W_hh + (gb * 32 + col) * 16 + hi * 8;
        u32x4 aw = { pk16(wr[0], wr[1]), pk16(wr[2], wr[3]),
                     pk16(wr[4], wr[5]), pk16(wr[6], wr[7]) };
        afrag[gb] = __builtin_bit_cast(f16x8, aw);
    }

    // ---- bias & W_ih in D-layout: reg r -> gu = gb*32 + (r&3) + 8*(r>>2) + 4*hi ----
    float biasv[2][16], wihv[2][16];
    #pragma unroll
    for (int gb = 0; gb < 2; ++gb)
        #pragma unroll
        for (int q = 0; q < 4; ++q) {
            const int gu = gb * 32 + 8 * q + 4 * hi;
            #pragma unroll
            for (int e = 0; e < 4; ++e) {
                biasv[gb][4 * q + e] = b_ih[gu + e] + b_hh[gu + e];
                wihv[gb][4 * q + e]  = W_ih[gu + e];
            }
        }

    // ---- state: c,h for (rb in {lo,hi}) x 8 units; unit(u)=(u&3)+8*(u>>2)+4*hi ----
    float c[2][8], h[2][8];
    #pragma unroll
    for (int rb = 0; rb < 2; ++rb)
        #pragma unroll
        for (int u = 0; u < 8; ++u) { c[rb][u] = 0.0f; h[rb][u] = 0.0f; }

    // B fragments (h^T). B[k][n]: n=lane&31, k=hi*8+2*dw+(lo/hi half). Start zero.
    u32x4 bz = { 0u, 0u, 0u, 0u };
    f16x8 bfrag[2];
    bfrag[0] = __builtin_bit_cast(f16x8, bz);
    bfrag[1] = __builtin_bit_cast(f16x8, bz);

    #pragma unroll 1   // rolled: ~550-instr body stays in I$; weights stay in regs
    for (int t = 0; t < 7; ++t) {
        const float xt_lo = mobility[r_lo * 7 + t];
        const float xt_hi = mobility[r_hi * 7 + t];

        f32x16 acc[2][2];
        #pragma unroll
        for (int gb = 0; gb < 2; ++gb)
            #pragma unroll
            for (int rb = 0; rb < 2; ++rb) {
                const float xt = rb ? xt_hi : xt_lo;
                f32x16 cin;
                #pragma unroll
                for (int r = 0; r < 16; ++r)
                    cin[r] = fmaf(xt, wihv[gb][r], biasv[gb][r]);
                acc[gb][rb] = __builtin_amdgcn_mfma_f32_32x32x16_f16(
                    afrag[gb], bfrag[rb], cin, 0, 0, 0);
            }

        // elementwise LSTM update, fully lane-local; then repack h -> B frags
        #pragma unroll
        for (int rb = 0; rb < 2; ++rb) {
            #pragma unroll
            for (int u = 0; u < 8; ++u) {
                float iv = sig_fast (acc[0][rb][u]);
                float fv = sig_fast (acc[0][rb][u + 8]);
                float gv = tanh_fast(acc[1][rb][u]);
                float ov = sig_fast (acc[1][rb][u + 8]);
                float cn = fmaf(fv, c[rb][u], iv * gv);
                c[rb][u] = cn;
                h[rb][u] = ov * tanh_fast(cn);
            }
            // q0..q3 = f16 pairs of own units; partner lane (^32) holds the
            // complementary units of the SAME two rows -> one swap fills B.
            unsigned q0 = pk16(h[rb][0], h[rb][1]);
            unsigned q1 = pk16(h[rb][2], h[rb][3]);
            unsigned q2 = pk16(h[rb][4], h[rb][5]);
            unsigned q3 = pk16(h[rb][6], h[rb][7]);
            auto s02 = __builtin_amdgcn_permlane32_swap(q0, q2, false, false);
            auto s13 = __builtin_amdgcn_permlane32_swap(q1, q3, false, false);
            u32x4 bw = { s02[0], s13[0], s02[1], s13[1] };
            bfrag[rb] = __builtin_bit_cast(f16x8, bw);
        }
    }

    // ---- redistribute h: wave-layout -> one row per thread ----
    #pragma unroll
    for (int rb = 0; rb < 2; ++rb) {
        const int rr = wib * 64 + col + rb * 32;
        #pragma unroll
        for (int u = 0; u < 8; ++u)
            hbuf[rr][(u & 3) + 4 * hi + 8 * (u >> 2)] = h[rb][u];
    }
    __syncthreads();

    // ---- fc stage: thread tid owns block-local row tid ----
    const int grow = blockRow0 + tid;

    float x19[19];
    #pragma unroll
    for (int k = 0; k < 16; ++k) x19[k] = hbuf[tid][k];

    float ctl[5];
    #pragma unroll
    for (int k = 0; k < 5; ++k) ctl[k] = controls[grow * 5 + k];
    #pragma unroll
    for (int j = 0; j < 3; ++j) {
        float a = b_cc[j];
        #pragma unroll
        for (int k = 0; k < 5; ++k) a = fmaf(ctl[k], W_cc[j * 5 + k], a);
        x19[16 + j] = a;
    }

    v2f t12[8];
    #pragma unroll
    for (int j = 0; j < 16; ++j) {
        float a = b1[j];
        #pragma unroll
        for (int k = 0; k < 19; ++k) a = fmaf(x19[k], W1[j * 19 + k], a);
        t12[j >> 1][j & 1] = tanh_fast(a);
    }
    v2f t22[8];
    #pragma unroll
    for (int j = 0; j < 16; ++j) {
        const v2f* w2row = (const v2f*)(W2 + j * 16);
        v2f a = t12[0] * w2row[0];
        #pragma unroll
        for (int p = 1; p < 8; ++p) a = __builtin_elementwise_fma(t12[p], w2row[p], a);
        t22[j >> 1][j & 1] = tanh_fast(a.x + a.y + b2[j]);
    }
    const v2f* w3p = (const v2f*)W3;
    v2f a3 = t22[0] * w3p[0];
    #pragma unroll
    for (int p = 1; p < 8; ++p) a3 = __builtin_elementwise_fma(t22[p], w3p[p], a3);
    const float r = a3.x + a3.y + b3[0];
    if (grow < Btot) out[grow] = fmaxf(r, 0.0f);
}

extern "C" void kernel_launch(void* const* d_in, const int* in_sizes, int n_in,
                              void* d_out, int out_size, void* d_ws, size_t ws_size,
                              hipStream_t stream) {
    const float* mobility = (const float*)d_in[0];
    const float* controls = (const float*)d_in[1];
    // d_in[2] = last : unused by the reference
    const float* W_cc = (const float*)d_in[3];
    const float* b_cc = (const float*)d_in[4];
    const float* W_ih = (const float*)d_in[5];
    const float* W_hh = (const float*)d_in[6];
    const float* b_ih = (const float*)d_in[7];
    const float* b_hh = (const float*)d_in[8];
    const float* W1   = (const float*)d_in[9];
    const float* b1   = (const float*)d_in[10];
    const float* W2   = (const float*)d_in[11];
    const float* b2   = (const float*)d_in[12];
    const float* W3   = (const float*)d_in[13];
    const float* b3   = (const float*)d_in[14];
    float* out = (float*)d_out;

    const int Btot = in_sizes[0] / 7;          // 1048576
    const int grid = (Btot + 255) / 256;       // 256 rows per block (4 waves x 64)

    lstm_mfma_kernel<<<grid, 256, 0, stream>>>(
        mobility, controls, W_cc, b_cc, W_ih, W_hh, b_ih, b_hh,
        W1, b1, W2, b2, W3, b3, out, Btot);
}

// Round 5
// 138.276 us; speedup vs baseline: 4.8338x; 1.2176x over previous
//
#include <hip/hip_runtime.h>
#include <hip/hip_bf16.h>

typedef _Float16 f16x8 __attribute__((ext_vector_type(8)));
typedef float    f32x16 __attribute__((ext_vector_type(16)));
typedef float    v2f   __attribute__((ext_vector_type(2)));
typedef unsigned u32x4 __attribute__((ext_vector_type(4)));

#define LOG2E 1.442695040888963f

__device__ __forceinline__ float tanh_fast(float x) {
    float e = __builtin_amdgcn_exp2f((2.0f * LOG2E) * x);
    return 1.0f - 2.0f * __builtin_amdgcn_rcpf(e + 1.0f);
}
__device__ __forceinline__ unsigned pk16(float a, float b) {
    return __builtin_bit_cast(unsigned, __builtin_amdgcn_cvt_pkrtz(a, b));
}

// Per wave: 64 batch rows; per step: G^T[64 gu][64 rows] = W_hh'[64x16] @ h^T[16x64]
// via 4x mfma_f32_32x32x16_f16. All gate rows PRESCALED by the exp2 argument
// factor (i,f,o: -log2e ; g: +2log2e) so each activation starts at exp2(acc).
// c is kept scaled: c' = 2*log2e*c, so exp2(c') = e^{2c} directly.
// Fused divisions: i*g = (eg-1)/((1+ei)(eg+1)), o*tanh(c) = (ec-1)/((1+eo)(ec+1)).
__global__ __launch_bounds__(256) void lstm_mfma_kernel(
    const float* __restrict__ mobility,  // [B,7]
    const float* __restrict__ controls,  // [B,5]
    const float* __restrict__ W_cc, const float* __restrict__ b_cc,
    const float* __restrict__ W_ih, const float* __restrict__ W_hh,
    const float* __restrict__ b_ih, const float* __restrict__ b_hh,
    const float* __restrict__ W1,  const float* __restrict__ b1,
    const float* __restrict__ W2,  const float* __restrict__ b2,
    const float* __restrict__ W3,  const float* __restrict__ b3,
    float* __restrict__ out, int Btot)
{
    __shared__ float hbuf[256][17];   // stride 17: bijective mod 32 -> conflict-free

    const int tid  = threadIdx.x;
    const int lane = tid & 63;
    const int wib  = tid >> 6;
    const int col  = lane & 31;
    const int hi   = lane >> 5;

    const int blockRow0 = blockIdx.x * 256;
    const int r_lo = blockRow0 + wib * 64 + col;
    const int r_hi = r_lo + 32;

    // ---- preload mobility (hide HBM latency under prologue) ----
    float mlo[7], mhi[7];
    #pragma unroll
    for (int t = 0; t < 7; ++t) { mlo[t] = mobility[r_lo * 7 + t]; mhi[t] = mobility[r_hi * 7 + t]; }

    // ---- A fragments: W_hh * rowscale -> f16. A[m=gu][k]: m=lane&31(+32gb), k=hi*8+e
    // gb=0 rows 0-31 (i,f): scale -log2e. gb=1 rows 32-63 (g,o): col<16 ? 2log2e : -log2e.
    f16x8 afrag[2];
    #pragma unroll
    for (int gb = 0; gb < 2; ++gb) {
        const float s = (gb == 0) ? -LOG2E : ((col < 16) ? 2.0f * LOG2E : -LOG2E);
        const float* wr = W_hh + (gb * 32 + col) * 16 + hi * 8;
        u32x4 aw = { pk16(s * wr[0], s * wr[1]), pk16(s * wr[2], s * wr[3]),
                     pk16(s * wr[4], s * wr[5]), pk16(s * wr[6], s * wr[7]) };
        afrag[gb] = __builtin_bit_cast(f16x8, aw);
    }

    // ---- bias & W_ih in D-layout, prescaled; stored as v2f for pk-FMA cin ----
    v2f biasv[2][8], wihv[2][8];
    #pragma unroll
    for (int gb = 0; gb < 2; ++gb)
        #pragma unroll
        for (int q = 0; q < 4; ++q) {
            const int gu = gb * 32 + 8 * q + 4 * hi;
            const float s = (gu < 32) ? -LOG2E : ((gu < 48) ? 2.0f * LOG2E : -LOG2E);
            #pragma unroll
            for (int e = 0; e < 4; ++e) {
                biasv[gb][2 * q + (e >> 1)][e & 1] = s * (b_ih[gu + e] + b_hh[gu + e]);
                wihv [gb][2 * q + (e >> 1)][e & 1] = s * W_ih[gu + e];
            }
        }

    float c[2][8], h[2][8];
    #pragma unroll
    for (int rb = 0; rb < 2; ++rb)
        #pragma unroll
        for (int u = 0; u < 8; ++u) { c[rb][u] = 0.0f; h[rb][u] = 0.0f; }

    u32x4 bz = { 0u, 0u, 0u, 0u };
    f16x8 bfrag[2];
    bfrag[0] = __builtin_bit_cast(f16x8, bz);
    bfrag[1] = __builtin_bit_cast(f16x8, bz);

    #pragma unroll 1
    for (int t = 0; t < 7; ++t) {
        f32x16 acc[2][2];
        #pragma unroll
        for (int gb = 0; gb < 2; ++gb)
            #pragma unroll
            for (int rb = 0; rb < 2; ++rb) {
                const float xt = rb ? mhi[t] : mlo[t];
                f32x16 cin;
                v2f* cp = (v2f*)&cin;
                #pragma unroll
                for (int p2 = 0; p2 < 8; ++p2) {
                    v2f xv = { xt, xt };
                    cp[p2] = __builtin_elementwise_fma(xv, wihv[gb][p2], biasv[gb][p2]);
                }
                acc[gb][rb] = __builtin_amdgcn_mfma_f32_32x32x16_f16(
                    afrag[gb], bfrag[rb], cin, 0, 0, 0);
            }

        #pragma unroll
        for (int rb = 0; rb < 2; ++rb) {
            #pragma unroll
            for (int u = 0; u < 8; ++u) {
                const float ea = __builtin_amdgcn_exp2f(acc[0][rb][u]);      // e^{-gi}
                const float ef = __builtin_amdgcn_exp2f(acc[0][rb][u + 8]);  // e^{-gf}
                const float eb = __builtin_amdgcn_exp2f(acc[1][rb][u]);      // e^{2gg}
                const float eo = __builtin_amdgcn_exp2f(acc[1][rb][u + 8]);  // e^{-go}
                const float fv  = __builtin_amdgcn_rcpf(1.0f + ef);          // f
                const float p   = 1.0f + ea;
                const float den = fmaf(p, eb, p);                            // (1+ei)(eg+1)
                const float r1  = __builtin_amdgcn_rcpf(den);
                const float num = fmaf(eb, 2.0f * LOG2E, -2.0f * LOG2E);     // 2log2e*(eg-1)
                const float igs = num * r1;                                  // 2log2e * i*g
                const float cs  = fmaf(fv, c[rb][u], igs);                   // c' (scaled)
                c[rb][u] = cs;
                const float ec  = __builtin_amdgcn_exp2f(cs);                // e^{2c}
                const float ph  = 1.0f + eo;
                const float dh  = fmaf(ph, ec, ph);                          // (1+eo)(ec+1)
                const float r2  = __builtin_amdgcn_rcpf(dh);
                h[rb][u] = (ec - 1.0f) * r2;                                 // o*tanh(c)
            }
            unsigned q0 = pk16(h[rb][0], h[rb][1]);
            unsigned q1 = pk16(h[rb][2], h[rb][3]);
            unsigned q2 = pk16(h[rb][4], h[rb][5]);
            unsigned q3 = pk16(h[rb][6], h[rb][7]);
            auto s02 = __builtin_amdgcn_permlane32_swap(q0, q2, false, false);
            auto s13 = __builtin_amdgcn_permlane32_swap(q1, q3, false, false);
            u32x4 bw = { s02[0], s13[0], s02[1], s13[1] };
            bfrag[rb] = __builtin_bit_cast(f16x8, bw);
        }
    }

    // ---- redistribute h: wave-layout -> one row per thread ----
    #pragma unroll
    for (int rb = 0; rb < 2; ++rb) {
        const int rr = wib * 64 + col + rb * 32;
        #pragma unroll
        for (int u = 0; u < 8; ++u)
            hbuf[rr][(u & 3) + 4 * hi + 8 * (u >> 2)] = h[rb][u];
    }
    __syncthreads();

    // ---- fc stage: thread tid owns block-local row tid ----
    const int grow = blockRow0 + tid;

    float x19[19];
    #pragma unroll
    for (int k = 0; k < 16; ++k) x19[k] = hbuf[tid][k];

    float ctl[5];
    #pragma unroll
    for (int k = 0; k < 5; ++k) ctl[k] = controls[grow * 5 + k];
    #pragma unroll
    for (int j = 0; j < 3; ++j) {
        float a = b_cc[j];
        #pragma unroll
        for (int k = 0; k < 5; ++k) a = fmaf(ctl[k], W_cc[j * 5 + k], a);
        x19[16 + j] = a;
    }

    v2f t12[8];
    #pragma unroll
    for (int j = 0; j < 16; ++j) {
        float a = b1[j];
        #pragma unroll
        for (int k = 0; k < 19; ++k) a = fmaf(x19[k], W1[j * 19 + k], a);
        t12[j >> 1][j & 1] = tanh_fast(a);
    }
    v2f t22[8];
    #pragma unroll
    for (int j = 0; j < 16; ++j) {
        const v2f* w2row = (const v2f*)(W2 + j * 16);
        v2f a = t12[0] * w2row[0];
        #pragma unroll
        for (int p = 1; p < 8; ++p) a = __builtin_elementwise_fma(t12[p], w2row[p], a);
        t22[j >> 1][j & 1] = tanh_fast(a.x + a.y + b2[j]);
    }
    const v2f* w3p = (const v2f*)W3;
    v2f a3 = t22[0] * w3p[0];
    #pragma unroll
    for (int p = 1; p < 8; ++p) a3 = __builtin_elementwise_fma(t22[p], w3p[p], a3);
    const float r = a3.x + a3.y + b3[0];
    if (grow < Btot) out[grow] = fmaxf(r, 0.0f);
}

extern "C" void kernel_launch(void* const* d_in, const int* in_sizes, int n_in,
                              void* d_out, int out_size, void* d_ws, size_t ws_size,
                              hipStream_t stream) {
    const float* mobility = (const float*)d_in[0];
    const float* controls = (const float*)d_in[1];
    // d_in[2] = last : unused by the reference
    const float* W_cc = (const float*)d_in[3];
    const float* b_cc = (const float*)d_in[4];
    const float* W_ih = (const float*)d_in[5];
    const float* W_hh = (const float*)d_in[6];
    const float* b_ih = (const float*)d_in[7];
    const float* b_hh = (const float*)d_in[8];
    const float* W1   = (const float*)d_in[9];
    const float* b1   = (const float*)d_in[10];
    const float* W2   = (const float*)d_in[11];
    const float* b2   = (const float*)d_in[12];
    const float* W3   = (const float*)d_in[13];
    const float* b3   = (const float*)d_in[14];
    float* out = (float*)d_out;

    const int Btot = in_sizes[0] / 7;          // 1048576
    const int grid = (Btot + 255) / 256;       // 256 rows per block (4 waves x 64)

    lstm_mfma_kernel<<<grid, 256, 0, stream>>>(
        mobility, controls, W_cc, b_cc, W_ih, W_hh, b_ih, b_hh,
        W1, b1, W2, b2, W3, b3, out, Btot);
}

// Round 6
// 129.365 us; speedup vs baseline: 5.1668x; 1.0689x over previous
//
#include <hip/hip_runtime.h>
#include <hip/hip_bf16.h>

typedef _Float16 f16x8 __attribute__((ext_vector_type(8)));
typedef float    f32x16 __attribute__((ext_vector_type(16)));
typedef float    v2f   __attribute__((ext_vector_type(2)));
typedef unsigned u32x4 __attribute__((ext_vector_type(4)));

#define LOG2E 1.442695040888963f

__device__ __forceinline__ unsigned pk16(float a, float b) {
    return __builtin_bit_cast(unsigned, __builtin_amdgcn_cvt_pkrtz(a, b));
}

// Per wave: 64 batch rows; per step: G^T[64 gu][64 rows] = W_hh'[64x16] @ h^T[16x64]
// via 4x mfma_f32_32x32x16_f16. Gate rows PRESCALED by the exp2 argument factor
// (i,f,o: -log2e ; g: +2log2e); c kept scaled (c' = 2log2e*c).
// rcp-minimized: c-update uses ONE rcp (merged f / i*g denominators);
// h-update uses ONE rcp per TWO units (pairwise-merged denominators).
__global__ __launch_bounds__(256) void lstm_mfma_kernel(
    const float* __restrict__ mobility,  // [B,7]
    const float* __restrict__ controls,  // [B,5]
    const float* __restrict__ W_cc, const float* __restrict__ b_cc,
    const float* __restrict__ W_ih, const float* __restrict__ W_hh,
    const float* __restrict__ b_ih, const float* __restrict__ b_hh,
    const float* __restrict__ W1,  const float* __restrict__ b1,
    const float* __restrict__ W2,  const float* __restrict__ b2,
    const float* __restrict__ W3,  const float* __restrict__ b3,
    float* __restrict__ out, int Btot)
{
    __shared__ float hbuf[256][17];   // stride 17: conflict-free

    const int tid  = threadIdx.x;
    const int lane = tid & 63;
    const int wib  = tid >> 6;
    const int col  = lane & 31;
    const int hi   = lane >> 5;

    const int blockRow0 = blockIdx.x * 256;
    const int r_lo = blockRow0 + wib * 64 + col;
    const int r_hi = r_lo + 32;

    float mlo[7], mhi[7];
    #pragma unroll
    for (int t = 0; t < 7; ++t) { mlo[t] = mobility[r_lo * 7 + t]; mhi[t] = mobility[r_hi * 7 + t]; }

    // ---- A fragments: W_hh * rowscale -> f16 ----
    f16x8 afrag[2];
    #pragma unroll
    for (int gb = 0; gb < 2; ++gb) {
        const float s = (gb == 0) ? -LOG2E : ((col < 16) ? 2.0f * LOG2E : -LOG2E);
        const float* wr = W_hh + (gb * 32 + col) * 16 + hi * 8;
        u32x4 aw = { pk16(s * wr[0], s * wr[1]), pk16(s * wr[2], s * wr[3]),
                     pk16(s * wr[4], s * wr[5]), pk16(s * wr[6], s * wr[7]) };
        afrag[gb] = __builtin_bit_cast(f16x8, aw);
    }

    // ---- bias & W_ih in D-layout, prescaled ----
    v2f biasv[2][8], wihv[2][8];
    #pragma unroll
    for (int gb = 0; gb < 2; ++gb)
        #pragma unroll
        for (int q = 0; q < 4; ++q) {
            const int gu = gb * 32 + 8 * q + 4 * hi;
            const float s = (gu < 32) ? -LOG2E : ((gu < 48) ? 2.0f * LOG2E : -LOG2E);
            #pragma unroll
            for (int e = 0; e < 4; ++e) {
                biasv[gb][2 * q + (e >> 1)][e & 1] = s * (b_ih[gu + e] + b_hh[gu + e]);
                wihv [gb][2 * q + (e >> 1)][e & 1] = s * W_ih[gu + e];
            }
        }

    float c[2][8], h[2][8];
    #pragma unroll
    for (int rb = 0; rb < 2; ++rb)
        #pragma unroll
        for (int u = 0; u < 8; ++u) { c[rb][u] = 0.0f; h[rb][u] = 0.0f; }

    u32x4 bz = { 0u, 0u, 0u, 0u };
    f16x8 bfrag[2];
    bfrag[0] = __builtin_bit_cast(f16x8, bz);
    bfrag[1] = __builtin_bit_cast(f16x8, bz);

    #pragma unroll 1
    for (int t = 0; t < 7; ++t) {
        f32x16 acc[2][2];
        #pragma unroll
        for (int gb = 0; gb < 2; ++gb)
            #pragma unroll
            for (int rb = 0; rb < 2; ++rb) {
                const float xt = rb ? mhi[t] : mlo[t];
                f32x16 cin;
                v2f* cp = (v2f*)&cin;
                #pragma unroll
                for (int p2 = 0; p2 < 8; ++p2) {
                    v2f xv = { xt, xt };
                    cp[p2] = __builtin_elementwise_fma(xv, wihv[gb][p2], biasv[gb][p2]);
                }
                acc[gb][rb] = __builtin_amdgcn_mfma_f32_32x32x16_f16(
                    afrag[gb], bfrag[rb], cin, 0, 0, 0);
            }

        #pragma unroll
        for (int rb = 0; rb < 2; ++rb) {
            float dh[8], nh[8];
            #pragma unroll
            for (int u = 0; u < 8; ++u) {
                const float ea = __builtin_amdgcn_exp2f(acc[0][rb][u]);      // e^{-gi}
                const float ef = __builtin_amdgcn_exp2f(acc[0][rb][u + 8]);  // e^{-gf}
                const float eb = __builtin_amdgcn_exp2f(acc[1][rb][u]);      // e^{2gg}
                const float eo = __builtin_amdgcn_exp2f(acc[1][rb][u + 8]);  // e^{-go}
                // cs = [c*(1+ea)(eb+1) + 2L(eb-1)(1+ef)] / [(1+ef)(1+ea)(eb+1)]
                const float pf   = 1.0f + ef;
                const float pa   = 1.0f + ea;
                const float den1 = fmaf(pa, eb, pa);                          // (1+ea)(eb+1)
                const float D    = den1 * pf;
                const float rD   = __builtin_amdgcn_rcpf(D);
                const float num  = fmaf(eb, 2.0f * LOG2E, -2.0f * LOG2E);     // 2L(eb-1)
                const float m1   = num * pf;
                const float cn   = fmaf(c[rb][u], den1, m1);
                const float cs   = cn * rD;
                c[rb][u] = cs;
                const float ec   = __builtin_amdgcn_exp2f(cs);                // e^{2c}
                const float ph   = 1.0f + eo;
                dh[u] = fmaf(ph, ec, ph);                                     // (1+eo)(ec+1)
                nh[u] = ec - 1.0f;
            }
            // pairwise-merged h division: h_u = nh_u*dh_v/(dh_u*dh_v), etc.
            #pragma unroll
            for (int u = 0; u < 8; u += 2) {
                const float P  = dh[u] * dh[u + 1];
                const float rP = __builtin_amdgcn_rcpf(P);
                h[rb][u]     = (nh[u]     * dh[u + 1]) * rP;
                h[rb][u + 1] = (nh[u + 1] * dh[u])     * rP;
            }
            unsigned q0 = pk16(h[rb][0], h[rb][1]);
            unsigned q1 = pk16(h[rb][2], h[rb][3]);
            unsigned q2 = pk16(h[rb][4], h[rb][5]);
            unsigned q3 = pk16(h[rb][6], h[rb][7]);
            auto s02 = __builtin_amdgcn_permlane32_swap(q0, q2, false, false);
            auto s13 = __builtin_amdgcn_permlane32_swap(q1, q3, false, false);
            u32x4 bw = { s02[0], s13[0], s02[1], s13[1] };
            bfrag[rb] = __builtin_bit_cast(f16x8, bw);
        }
    }

    // ---- redistribute h: wave-layout -> one row per thread ----
    #pragma unroll
    for (int rb = 0; rb < 2; ++rb) {
        const int rr = wib * 64 + col + rb * 32;
        #pragma unroll
        for (int u = 0; u < 8; ++u)
            hbuf[rr][(u & 3) + 4 * hi + 8 * (u >> 2)] = h[rb][u];
    }
    __syncthreads();

    // ---- fc stage: thread tid owns block-local row tid ----
    const int grow = blockRow0 + tid;

    float x19[19];
    #pragma unroll
    for (int k = 0; k < 16; ++k) x19[k] = hbuf[tid][k];

    float ctl[5];
    #pragma unroll
    for (int k = 0; k < 5; ++k) ctl[k] = controls[grow * 5 + k];
    #pragma unroll
    for (int j = 0; j < 3; ++j) {
        float a = b_cc[j];
        #pragma unroll
        for (int k = 0; k < 5; ++k) a = fmaf(ctl[k], W_cc[j * 5 + k], a);
        x19[16 + j] = a;
    }

    // fc1: Linear(19->16); tanh via pairwise-merged rcp:
    // tanh(a) = 1 - 2*dv/(d*dv) with d = exp2(2L*a)+1
    float d1[16];
    #pragma unroll
    for (int j = 0; j < 16; ++j) {
        float a = b1[j];
        #pragma unroll
        for (int k = 0; k < 19; ++k) a = fmaf(x19[k], W1[j * 19 + k], a);
        d1[j] = __builtin_amdgcn_exp2f((2.0f * LOG2E) * a) + 1.0f;
    }
    v2f t12[8];
    #pragma unroll
    for (int j = 0; j < 16; j += 2) {
        const float rP = __builtin_amdgcn_rcpf(d1[j] * d1[j + 1]);
        t12[j >> 1][0] = fmaf(-2.0f * d1[j + 1], rP, 1.0f);
        t12[j >> 1][1] = fmaf(-2.0f * d1[j],     rP, 1.0f);
    }

    // fc2: Linear(16->16) + tanh (packed fma, pairwise-merged rcp)
    float d2[16];
    #pragma unroll
    for (int j = 0; j < 16; ++j) {
        const v2f* w2row = (const v2f*)(W2 + j * 16);
        v2f a = t12[0] * w2row[0];
        #pragma unroll
        for (int p = 1; p < 8; ++p) a = __builtin_elementwise_fma(t12[p], w2row[p], a);
        d2[j] = __builtin_amdgcn_exp2f((2.0f * LOG2E) * (a.x + a.y + b2[j])) + 1.0f;
    }
    v2f t22[8];
    #pragma unroll
    for (int j = 0; j < 16; j += 2) {
        const float rP = __builtin_amdgcn_rcpf(d2[j] * d2[j + 1]);
        t22[j >> 1][0] = fmaf(-2.0f * d2[j + 1], rP, 1.0f);
        t22[j >> 1][1] = fmaf(-2.0f * d2[j],     rP, 1.0f);
    }

    // fc3: Linear(16->1) + ReLU
    const v2f* w3p = (const v2f*)W3;
    v2f a3 = t22[0] * w3p[0];
    #pragma unroll
    for (int p = 1; p < 8; ++p) a3 = __builtin_elementwise_fma(t22[p], w3p[p], a3);
    const float r = a3.x + a3.y + b3[0];
    if (grow < Btot) out[grow] = fmaxf(r, 0.0f);
}

extern "C" void kernel_launch(void* const* d_in, const int* in_sizes, int n_in,
                              void* d_out, int out_size, void* d_ws, size_t ws_size,
                              hipStream_t stream) {
    const float* mobility = (const float*)d_in[0];
    const float* controls = (const float*)d_in[1];
    // d_in[2] = last : unused by the reference
    const float* W_cc = (const float*)d_in[3];
    const float* b_cc = (const float*)d_in[4];
    const float* W_ih = (const float*)d_in[5];
    const float* W_hh = (const float*)d_in[6];
    const float* b_ih = (const float*)d_in[7];
    const float* b_hh = (const float*)d_in[8];
    const float* W1   = (const float*)d_in[9];
    const float* b1   = (const float*)d_in[10];
    const float* W2   = (const float*)d_in[11];
    const float* b2   = (const float*)d_in[12];
    const float* W3   = (const float*)d_in[13];
    const float* b3   = (const float*)d_in[14];
    float* out = (float*)d_out;

    const int Btot = in_sizes[0] / 7;          // 1048576
    const int grid = (Btot + 255) / 256;       // 256 rows per block (4 waves x 64)

    lstm_mfma_kernel<<<grid, 256, 0, stream>>>(
        mobility, controls, W_cc, b_cc, W_ih, W_hh, b_ih, b_hh,
        W1, b1, W2, b2, W3, b3, out, Btot);
}